// Round 2
// baseline (15737.587 us; speedup 1.0000x reference)
//
#include <hip/hip_runtime.h>

typedef __bf16 bf16;
typedef __bf16 bf16x8 __attribute__((ext_vector_type(8)));
typedef float f32x4 __attribute__((ext_vector_type(4)));

#define T_STEPS 256
#define NWG 256

__device__ __forceinline__ float sigmoidf_(float v) { return 1.0f / (1.0f + __expf(-v)); }

// Monotonic global barrier: each WG's thread0 adds 1, spins until count >= goal.
// goal increases by NWG per barrier; count never resets (512*256 << 2^32).
__device__ __forceinline__ void gbar(unsigned int* bar, unsigned int goal) {
    __syncthreads();
    if (threadIdx.x == 0) {
        __threadfence();  // release: flush z/h/x writes toward coherent point
        __hip_atomic_fetch_add(bar, 1u, __ATOMIC_RELEASE, __HIP_MEMORY_SCOPE_AGENT);
        // relaxed spin (atomic agent-scope load reads coherent point, no cache inv per poll)
        while (__hip_atomic_load(bar, __ATOMIC_RELAXED, __HIP_MEMORY_SCOPE_AGENT) < goal)
            __builtin_amdgcn_s_sleep(1);
        __threadfence();  // acquire: invalidate L1/L2 so post-barrier loads are fresh
    }
    __syncthreads();
}

// ---------------------------------------------------------------------------
// Init: zero h0 (buffer 0), convert x slice 0 -> xb buffer 0, zero barrier.
// ---------------------------------------------------------------------------
__global__ void init_kernel(const float* __restrict__ x, bf16* __restrict__ xb0,
                            bf16* __restrict__ hb0, unsigned int* __restrict__ bar) {
    int gid = blockIdx.x * blockDim.x + threadIdx.x;  // 32768 threads
    #pragma unroll
    for (int i = 0; i < 4; ++i) {
        int idx = gid + i * 32768;
        xb0[idx] = (bf16)x[idx];
        hb0[idx] = (bf16)0.0f;
    }
    if (gid == 0) *bar = 0u;
}

// ---------------------------------------------------------------------------
// Persistent LSTM: 256 WGs x 512 thr, one per CU. WG = (tile = 16 hidden cols
// x 4 gates, kq = K-quarter). Weights live in VGPRs (bfrag[4][8]) for all 256
// steps; A-frags load straight from global xb/hb; z partials exchanged via P;
// cell state is one register per thread. Two global barriers per step.
// ---------------------------------------------------------------------------
__global__ __launch_bounds__(512, 2) void lstm_persist(
    const float* __restrict__ x,
    const float* __restrict__ Wf, const float* __restrict__ bfp,
    const float* __restrict__ Wi, const float* __restrict__ bip,
    const float* __restrict__ Wg, const float* __restrict__ bgp,
    const float* __restrict__ Wo, const float* __restrict__ bop,
    bf16* __restrict__ xb, bf16* __restrict__ hb,
    float* __restrict__ P, unsigned int* __restrict__ bar)
{
    const int wg   = blockIdx.x;
    const int tile = wg >> 2;      // 0..63 : hidden cols [16*tile, +16)
    const int kq   = wg & 3;       // K quarter: k in [512*kq, +512)
    const int tid  = threadIdx.x;
    const int lane = tid & 63;
    const int wv   = tid >> 6;     // 8 waves
    const int mq   = wv & 3;       // batch rows [32*mq, +32)
    const int kh   = wv >> 2;      // k-half within quarter
    const int l16  = lane & 15;
    const int l4   = lane >> 4;
    const int kbase = kq * 512 + kh * 256;
    const int kslot = kq * 2 + kh; // 0..7

    // ---- B fragments (persistent): gate g, k-step ks: W[n = tile*16+l16][k]
    const float* Wptr[4] = {Wf, Wi, Wg, Wo};
    bf16x8 bfrag[4][8];
    #pragma unroll
    for (int g = 0; g < 4; ++g) {
        const float* wrow = Wptr[g] + (size_t)(tile * 16 + l16) * 2048 + kbase + l4 * 8;
        #pragma unroll
        for (int ks = 0; ks < 8; ++ks) {
            float4 w0 = *(const float4*)(wrow + ks * 32);
            float4 w1 = *(const float4*)(wrow + ks * 32 + 4);
            bf16x8 b;
            b[0] = (bf16)w0.x; b[1] = (bf16)w0.y; b[2] = (bf16)w0.z; b[3] = (bf16)w0.w;
            b[4] = (bf16)w1.x; b[5] = (bf16)w1.y; b[6] = (bf16)w1.z; b[7] = (bf16)w1.w;
            bfrag[g][ks] = b;
        }
    }

    // ---- phase-B ownership: thread -> (batch row cb, col ccol), c in register
    const int cb   = kq * 32 + (tid >> 4);
    const int ccol = tid & 15;
    float bias[4];
    bias[0] = bfp[tile * 16 + ccol];  // gate0 -> i_t (ref naming swap)
    bias[1] = bip[tile * 16 + ccol];  // gate1 -> f_t
    bias[2] = bgp[tile * 16 + ccol];  // gate2 -> g_t
    bias[3] = bop[tile * 16 + ccol];  // gate3 -> o_t
    float creg = 0.0f;

    const int srow = mq * 32 + l16;
    const int koff = (kq < 2) ? kbase : (kbase - 1024);

    unsigned int goal = 0;
    for (int t = 0; t < T_STEPS; ++t) {
        // ================= phase A: z partial GEMM =================
        const bf16* Sb = ((kq < 2) ? xb : hb) + (t & 1) * 131072;
        const bf16* S0 = Sb + (size_t)srow * 1024 + koff + l4 * 8;

        f32x4 acc[2][4];
        #pragma unroll
        for (int mt = 0; mt < 2; ++mt)
            #pragma unroll
            for (int g = 0; g < 4; ++g) acc[mt][g] = (f32x4){0.f, 0.f, 0.f, 0.f};

        #pragma unroll
        for (int ksb = 0; ksb < 2; ++ksb) {
            bf16x8 af[4][2];
            #pragma unroll
            for (int ks = 0; ks < 4; ++ks)
                #pragma unroll
                for (int mt = 0; mt < 2; ++mt)
                    af[ks][mt] = *(const bf16x8*)(S0 + (ksb * 4 + ks) * 32 + mt * 16 * 1024);
            #pragma unroll
            for (int ks = 0; ks < 4; ++ks)
                #pragma unroll
                for (int mt = 0; mt < 2; ++mt)
                    #pragma unroll
                    for (int g = 0; g < 4; ++g)
                        acc[mt][g] = __builtin_amdgcn_mfma_f32_16x16x32_bf16(
                            af[ks][mt], bfrag[g][ksb * 4 + ks], acc[mt][g], 0, 0, 0);
        }

        // convert next x slice (consumed 2 barriers later)
        if (t + 1 < T_STEPS) {
            int gid = wg * 512 + tid;
            xb[((t + 1) & 1) * 131072 + gid] = (bf16)x[(size_t)(t + 1) * 131072 + gid];
        }

        // z partial stores: P[kslot][tile][b][n]
        {
            float* Pbase = P + (size_t)((kslot * 64 + tile) * 128) * 64;
            #pragma unroll
            for (int mt = 0; mt < 2; ++mt) {
                int b0 = mq * 32 + mt * 16 + l4 * 4;
                #pragma unroll
                for (int g = 0; g < 4; ++g) {
                    int n = g * 16 + l16;
                    #pragma unroll
                    for (int r = 0; r < 4; ++r)
                        Pbase[(size_t)(b0 + r) * 64 + n] = acc[mt][g][r];
                }
            }
        }

        goal += NWG; gbar(bar, goal);

        // ================= phase B: gate combine =================
        {
            float z[4];
            #pragma unroll
            for (int g = 0; g < 4; ++g) z[g] = bias[g];
            #pragma unroll
            for (int ks2 = 0; ks2 < 8; ++ks2) {
                const float* Pr = P + (size_t)((ks2 * 64 + tile) * 128 + cb) * 64;
                #pragma unroll
                for (int g = 0; g < 4; ++g) z[g] += Pr[g * 16 + ccol];
            }
            float ig = sigmoidf_(z[0]);
            float fg = sigmoidf_(z[1]);
            float gg = tanhf(z[2]);
            float og = sigmoidf_(z[3]);
            creg = fg * creg + ig * gg;
            hb[((t + 1) & 1) * 131072 + cb * 1024 + tile * 16 + ccol] = (bf16)(og * tanhf(creg));
        }

        goal += NWG; gbar(bar, goal);
    }
}

// ---------------------------------------------------------------------------
// logits = h_T @ Wout^T + bout (Wout converted inline from f32).
// ---------------------------------------------------------------------------
__global__ __launch_bounds__(512) void final_gemm_kernel(
    const bf16* __restrict__ hfin, const float* __restrict__ Wout,
    const float* __restrict__ bout, float* __restrict__ logits) {
    __shared__ alignas(16) bf16 Slds[128 * 72];
    const int tid  = threadIdx.x;
    const int lane = tid & 63;
    const int wave = tid >> 6;
    const int l16  = lane & 15;
    const int l4   = lane >> 4;
    const int n0   = blockIdx.x * 16;
    f32x4 acc = (f32x4){0.f, 0.f, 0.f, 0.f};
    for (int k0 = 0; k0 < 1024; k0 += 64) {
        #pragma unroll
        for (int i = 0; i < 2; ++i) {
            int cidx = tid + i * 512;
            int row = cidx >> 3, c8 = cidx & 7;
            *(uint4*)(&Slds[row * 72 + c8 * 8]) =
                *(const uint4*)(hfin + row * 1024 + k0 + c8 * 8);
        }
        __syncthreads();
        #pragma unroll
        for (int kk = 0; kk < 64; kk += 32) {
            const float* wrow = Wout + (size_t)(n0 + l16) * 1024 + k0 + kk + l4 * 8;
            float4 w0 = *(const float4*)(wrow);
            float4 w1 = *(const float4*)(wrow + 4);
            bf16x8 bfrag;
            bfrag[0] = (bf16)w0.x; bfrag[1] = (bf16)w0.y; bfrag[2] = (bf16)w0.z; bfrag[3] = (bf16)w0.w;
            bfrag[4] = (bf16)w1.x; bfrag[5] = (bf16)w1.y; bfrag[6] = (bf16)w1.z; bfrag[7] = (bf16)w1.w;
            bf16x8 afrag = *(const bf16x8*)(&Slds[(wave * 16 + l16) * 72 + kk + l4 * 8]);
            acc = __builtin_amdgcn_mfma_f32_16x16x32_bf16(afrag, bfrag, acc, 0, 0, 0);
        }
        __syncthreads();
    }
    float bv = bout[n0 + l16];
    #pragma unroll
    for (int r = 0; r < 4; ++r) {
        int m = wave * 16 + l4 * 4 + r;
        logits[m * 1024 + n0 + l16] = acc[r] + bv;
    }
}

// ---------------------------------------------------------------------------
// Row-wise log_softmax over 1024 logits. Grid 128 (one WG per batch row).
// ---------------------------------------------------------------------------
__global__ __launch_bounds__(256) void logsoftmax_kernel(
    const float* __restrict__ logits, float* __restrict__ out) {
    int b = blockIdx.x, tid = threadIdx.x;
    int lane = tid & 63, wv = tid >> 6;
    __shared__ float red[4];
    float v[4];
    float mx = -1e30f;
    #pragma unroll
    for (int i = 0; i < 4; ++i) {
        v[i] = logits[b * 1024 + i * 256 + tid];
        mx = fmaxf(mx, v[i]);
    }
    #pragma unroll
    for (int off = 1; off < 64; off <<= 1) mx = fmaxf(mx, __shfl_xor(mx, off));
    if (lane == 0) red[wv] = mx;
    __syncthreads();
    mx = fmaxf(fmaxf(red[0], red[1]), fmaxf(red[2], red[3]));
    float s = 0.f;
    #pragma unroll
    for (int i = 0; i < 4; ++i) s += __expf(v[i] - mx);
    #pragma unroll
    for (int off = 1; off < 64; off <<= 1) s += __shfl_xor(s, off);
    __syncthreads();
    if (lane == 0) red[wv] = s;
    __syncthreads();
    s = red[0] + red[1] + red[2] + red[3];
    float lse = mx + __logf(s);
    #pragma unroll
    for (int i = 0; i < 4; ++i) out[b * 1024 + i * 256 + tid] = v[i] - lse;
}

extern "C" void kernel_launch(void* const* d_in, const int* in_sizes, int n_in,
                              void* d_out, int out_size, void* d_ws, size_t ws_size,
                              hipStream_t stream) {
    const float* x    = (const float*)d_in[0];
    const float* Wf   = (const float*)d_in[1];
    const float* bfv  = (const float*)d_in[2];
    const float* Wi   = (const float*)d_in[3];
    const float* biv  = (const float*)d_in[4];
    const float* Wg   = (const float*)d_in[5];
    const float* bgv  = (const float*)d_in[6];
    const float* Wo   = (const float*)d_in[7];
    const float* bov  = (const float*)d_in[8];
    const float* Wout = (const float*)d_in[9];
    const float* bout = (const float*)d_in[10];
    float* out = (float*)d_out;

    // ws layout (~17.6 MB)
    char* p = (char*)d_ws;
    bf16* xbuf    = (bf16*)p;  p += (size_t)2 * 131072 * 2;          // x slice double-buffer
    bf16* hbuf    = (bf16*)p;  p += (size_t)2 * 131072 * 2;          // h double-buffer
    float* P      = (float*)p; p += (size_t)8 * 64 * 128 * 64 * 4;   // 16 MB z-partials
    float* logits = (float*)p; p += (size_t)131072 * 4;
    unsigned int* bar = (unsigned int*)p; p += 128;
    if (ws_size < (size_t)(p - (char*)d_ws)) return;  // ws too small: fail loudly

    init_kernel<<<128, 256, 0, stream>>>(x, xbuf, hbuf, bar);
    lstm_persist<<<NWG, 512, 0, stream>>>(x, Wf, bfv, Wi, biv, Wg, bgv, Wo, bov,
                                          xbuf, hbuf, P, bar);
    // final h is in hbuf buffer 0 (256 even)
    final_gemm_kernel<<<64, 512, 0, stream>>>(hbuf, Wout, bout, logits);
    logsoftmax_kernel<<<128, 256, 0, stream>>>(logits, out);
}

// Round 3
// 5856.971 us; speedup vs baseline: 2.6870x; 2.6870x over previous
//
#include <hip/hip_runtime.h>

typedef __bf16 bf16;
typedef __bf16 bf16x8 __attribute__((ext_vector_type(8)));
typedef float f32x4 __attribute__((ext_vector_type(4)));

#define T_STEPS 256
#define NWG 256

__device__ __forceinline__ float sigmoidf_(float v) { return 1.0f / (1.0f + __expf(-v)); }

// Split barrier: arrive (after h write) / wait (before h read). Monotonic count.
__device__ __forceinline__ void gwait(unsigned int* bar, unsigned int goal) {
    if (threadIdx.x == 0) {
        while (__hip_atomic_load(bar, __ATOMIC_RELAXED, __HIP_MEMORY_SCOPE_AGENT) < goal)
            __builtin_amdgcn_s_sleep(2);
        __threadfence();  // acquire: invalidate caches so h reads are fresh
    }
    __syncthreads();
}
__device__ __forceinline__ void garrive(unsigned int* bar) {
    __syncthreads();      // all threads' h stores drained (barrier implies vmcnt(0))
    if (threadIdx.x == 0) {
        __threadfence();  // release: flush this WG's h writes to coherent point
        __hip_atomic_fetch_add(bar, 1u, __ATOMIC_RELEASE, __HIP_MEMORY_SCOPE_AGENT);
    }
}

__global__ void init_kernel(bf16* __restrict__ hb0, unsigned int* __restrict__ bar) {
    int gid = blockIdx.x * blockDim.x + threadIdx.x;  // 32768 threads
    #pragma unroll
    for (int i = 0; i < 4; ++i) hb0[gid + i * 32768] = (bf16)0.0f;
    if (gid == 0) *bar = 0u;
}

// ---------------------------------------------------------------------------
// Persistent LSTM: 256 WGs x 512 thr (1/CU). WG = (mq = batch rows [32mq,+32),
// tile = hidden cols [16t,+16) x all 4 gates). Wave = (gpair, kq): B-frags
// 32n x 512k persistent in VGPRs (128 VGPR/lane, zero duplication). S=[x|h]
// tile in LDS (XOR-swizzled). Intra-WG K-reduction via LDS; c-state one
// register/thread; ONE global barrier per step, ~1 KB flushed per WG.
// ---------------------------------------------------------------------------
__global__ __launch_bounds__(512, 2) void lstm_persist(
    const float* __restrict__ x,
    const float* __restrict__ Wf, const float* __restrict__ bfp,
    const float* __restrict__ Wi, const float* __restrict__ bip,
    const float* __restrict__ Wg, const float* __restrict__ bgp,
    const float* __restrict__ Wo, const float* __restrict__ bop,
    bf16* __restrict__ hb, unsigned int* __restrict__ bar)
{
    __shared__ bf16 S[32 * 2048];     // 128 KB: rows pitch 2048 els, 16B-chunk c stored at c^(row&7)
    __shared__ float zbuf[6336];      // 25 KB: 6 partial bufs [32][33]; overlaid zfull [32][65]

    const int wg    = blockIdx.x;
    const int mq    = wg & 3;
    const int tile  = wg >> 2;
    const int tid   = threadIdx.x;
    const int lane  = tid & 63;
    const int w     = tid >> 6;
    const int kq    = w & 3;          // K quarter (0,1 = x half; 2,3 = h half)
    const int gpair = w >> 2;         // gates {0,1} or {2,3}
    const int l16   = lane & 15;
    const int l4    = lane >> 4;

    // ---- persistent B fragments: gate g = gpair*2+nt, k = kq*512 + ks*32 + l4*8
    bf16x8 bfrag[2][16];
    {
        const float* Wg0 = gpair ? Wg : Wf;
        const float* Wg1 = gpair ? Wo : Wi;
        #pragma unroll
        for (int nt = 0; nt < 2; ++nt) {
            const float* wrow = (nt ? Wg1 : Wg0) + (size_t)(tile * 16 + l16) * 2048 + kq * 512 + l4 * 8;
            #pragma unroll
            for (int ks = 0; ks < 16; ++ks) {
                float4 a = *(const float4*)(wrow + ks * 32);
                float4 b = *(const float4*)(wrow + ks * 32 + 4);
                bf16x8 f;
                f[0]=(bf16)a.x; f[1]=(bf16)a.y; f[2]=(bf16)a.z; f[3]=(bf16)a.w;
                f[4]=(bf16)b.x; f[5]=(bf16)b.y; f[6]=(bf16)b.z; f[7]=(bf16)b.w;
                bfrag[nt][ks] = f;
            }
        }
    }

    const int cb   = tid >> 4;        // combine ownership: local batch row
    const int ccol = tid & 15;        //                    hidden col
    const float bias0 = bfp[tile * 16 + ccol];   // gate0 -> i_t (ref naming swap)
    const float bias1 = bip[tile * 16 + ccol];   // gate1 -> f_t
    const float bias2 = bgp[tile * 16 + ccol];   // gate2 -> g_t
    const float bias3 = bop[tile * 16 + ccol];   // gate3 -> o_t
    float creg = 0.0f;

    unsigned int goal = 0;
    for (int t = 0; t < T_STEPS; ++t) {
        // ---- stage x half (immutable input, no dependency): overlaps barrier wait
        {
            const int row = tid >> 4, cl = tid & 15;
            const float* gsrc = x + (size_t)t * 131072 + (size_t)(mq * 32 + row) * 1024;
            #pragma unroll
            for (int j = 0; j < 8; ++j) {
                int c = cl + j * 16;               // chunk 0..127 (x half)
                float4 v0 = *(const float4*)(gsrc + c * 8);
                float4 v1 = *(const float4*)(gsrc + c * 8 + 4);
                bf16x8 f;
                f[0]=(bf16)v0.x; f[1]=(bf16)v0.y; f[2]=(bf16)v0.z; f[3]=(bf16)v0.w;
                f[4]=(bf16)v1.x; f[5]=(bf16)v1.y; f[6]=(bf16)v1.z; f[7]=(bf16)v1.w;
                int cp = c ^ (row & 7);
                *(bf16x8*)(&S[row * 2048 + cp * 8]) = f;
            }
        }
        if (t > 0) { goal += NWG; gwait(bar, goal); }   // h(t) ready (t=0: init kernel)
        // ---- stage h half via global_load_lds (bf16, 64 KB)
        {
            const bf16* hcur = hb + (t & 1) * 131072;
            #pragma unroll
            for (int r = 0; r < 4; ++r) {
                int row = w * 4 + r;
                #pragma unroll
                for (int q = 2; q < 4; ++q) {
                    int cp = q * 64 + lane;        // LDS slot; global chunk c = cp^(row&7)
                    int c  = cp ^ (row & 7);
                    const bf16* g = hcur + (size_t)(mq * 32 + row) * 1024 + (c - 128) * 8;
                    bf16* l = &S[row * 2048 + q * 512];
                    __builtin_amdgcn_global_load_lds(
                        (const __attribute__((address_space(1))) unsigned int*)g,
                        (__attribute__((address_space(3))) unsigned int*)l, 16, 0, 0);
                }
            }
        }
        __syncthreads();

        // ---- GEMM: wave computes 32m x 32n over its 512-wide k slice
        f32x4 acc[2][2];
        acc[0][0] = acc[0][1] = acc[1][0] = acc[1][1] = (f32x4){0.f, 0.f, 0.f, 0.f};
        #pragma unroll
        for (int ks = 0; ks < 16; ++ks) {
            bf16x8 af[2];
            #pragma unroll
            for (int mt = 0; mt < 2; ++mt) {
                int row = mt * 16 + l16;
                int c   = kq * 64 + ks * 4 + l4;
                int cp  = c ^ (l16 & 7);
                af[mt] = *(const bf16x8*)(&S[row * 2048 + cp * 8]);
            }
            #pragma unroll
            for (int mt = 0; mt < 2; ++mt)
                #pragma unroll
                for (int nt = 0; nt < 2; ++nt)
                    acc[mt][nt] = __builtin_amdgcn_mfma_f32_16x16x32_bf16(
                        af[mt], bfrag[nt][ks], acc[mt][nt], 0, 0, 0);
        }
        __syncthreads();

        // ---- intra-WG K-reduction (kq 1..3 -> kq 0), C/D layout row=l4*4+r col=l16
        if (kq != 0) {
            float* pb = zbuf + (gpair * 3 + (kq - 1)) * 1056;
            #pragma unroll
            for (int mt = 0; mt < 2; ++mt)
                #pragma unroll
                for (int nt = 0; nt < 2; ++nt)
                    #pragma unroll
                    for (int r = 0; r < 4; ++r)
                        pb[(mt * 16 + l4 * 4 + r) * 33 + nt * 16 + l16] = acc[mt][nt][r];
        }
        __syncthreads();
        if (kq == 0) {
            #pragma unroll
            for (int s = 0; s < 3; ++s) {
                const float* pb = zbuf + (gpair * 3 + s) * 1056;
                #pragma unroll
                for (int mt = 0; mt < 2; ++mt)
                    #pragma unroll
                    for (int nt = 0; nt < 2; ++nt)
                        #pragma unroll
                        for (int r = 0; r < 4; ++r)
                            acc[mt][nt][r] += pb[(mt * 16 + l4 * 4 + r) * 33 + nt * 16 + l16];
            }
        }
        __syncthreads();
        if (kq == 0) {  // write full z [32][64] (pitch 65) overlaid on zbuf
            #pragma unroll
            for (int mt = 0; mt < 2; ++mt)
                #pragma unroll
                for (int nt = 0; nt < 2; ++nt)
                    #pragma unroll
                    for (int r = 0; r < 4; ++r)
                        zbuf[(mt * 16 + l4 * 4 + r) * 65 + gpair * 32 + nt * 16 + l16] = acc[mt][nt][r];
        }
        __syncthreads();

        // ---- gate combine: thread owns (cb, ccol); c-state in register
        {
            float zi = zbuf[cb * 65 + 0  + ccol] + bias0;
            float zf = zbuf[cb * 65 + 16 + ccol] + bias1;
            float zg = zbuf[cb * 65 + 32 + ccol] + bias2;
            float zo = zbuf[cb * 65 + 48 + ccol] + bias3;
            float ig = sigmoidf_(zi), fg = sigmoidf_(zf);
            float gg = tanhf(zg),     og = sigmoidf_(zo);
            creg = fg * creg + ig * gg;
            hb[((t + 1) & 1) * 131072 + (size_t)(mq * 32 + cb) * 1024 + tile * 16 + ccol]
                = (bf16)(og * tanhf(creg));
        }
        garrive(bar);
    }
}

// ---------------------------------------------------------------------------
// logits = h_T @ Wout^T + bout (Wout converted inline from f32).
// ---------------------------------------------------------------------------
__global__ __launch_bounds__(512) void final_gemm_kernel(
    const bf16* __restrict__ hfin, const float* __restrict__ Wout,
    const float* __restrict__ bout, float* __restrict__ logits) {
    __shared__ alignas(16) bf16 Slds[128 * 72];
    const int tid  = threadIdx.x;
    const int lane = tid & 63;
    const int wave = tid >> 6;
    const int l16  = lane & 15;
    const int l4   = lane >> 4;
    const int n0   = blockIdx.x * 16;
    f32x4 acc = (f32x4){0.f, 0.f, 0.f, 0.f};
    for (int k0 = 0; k0 < 1024; k0 += 64) {
        #pragma unroll
        for (int i = 0; i < 2; ++i) {
            int cidx = tid + i * 512;
            int row = cidx >> 3, c8 = cidx & 7;
            *(uint4*)(&Slds[row * 72 + c8 * 8]) =
                *(const uint4*)(hfin + row * 1024 + k0 + c8 * 8);
        }
        __syncthreads();
        #pragma unroll
        for (int kk = 0; kk < 64; kk += 32) {
            const float* wrow = Wout + (size_t)(n0 + l16) * 1024 + k0 + kk + l4 * 8;
            float4 w0 = *(const float4*)(wrow);
            float4 w1 = *(const float4*)(wrow + 4);
            bf16x8 bfrag;
            bfrag[0]=(bf16)w0.x; bfrag[1]=(bf16)w0.y; bfrag[2]=(bf16)w0.z; bfrag[3]=(bf16)w0.w;
            bfrag[4]=(bf16)w1.x; bfrag[5]=(bf16)w1.y; bfrag[6]=(bf16)w1.z; bfrag[7]=(bf16)w1.w;
            bf16x8 afrag = *(const bf16x8*)(&Slds[(wave * 16 + l16) * 72 + kk + l4 * 8]);
            acc = __builtin_amdgcn_mfma_f32_16x16x32_bf16(afrag, bfrag, acc, 0, 0, 0);
        }
        __syncthreads();
    }
    float bv = bout[n0 + l16];
    #pragma unroll
    for (int r = 0; r < 4; ++r) {
        int m = wave * 16 + l4 * 4 + r;
        logits[m * 1024 + n0 + l16] = acc[r] + bv;
    }
}

// ---------------------------------------------------------------------------
// Row-wise log_softmax over 1024 logits. Grid 128 (one WG per batch row).
// ---------------------------------------------------------------------------
__global__ __launch_bounds__(256) void logsoftmax_kernel(
    const float* __restrict__ logits, float* __restrict__ out) {
    int b = blockIdx.x, tid = threadIdx.x;
    int lane = tid & 63, wv = tid >> 6;
    __shared__ float red[4];
    float v[4];
    float mx = -1e30f;
    #pragma unroll
    for (int i = 0; i < 4; ++i) {
        v[i] = logits[b * 1024 + i * 256 + tid];
        mx = fmaxf(mx, v[i]);
    }
    #pragma unroll
    for (int off = 1; off < 64; off <<= 1) mx = fmaxf(mx, __shfl_xor(mx, off));
    if (lane == 0) red[wv] = mx;
    __syncthreads();
    mx = fmaxf(fmaxf(red[0], red[1]), fmaxf(red[2], red[3]));
    float s = 0.f;
    #pragma unroll
    for (int i = 0; i < 4; ++i) s += __expf(v[i] - mx);
    #pragma unroll
    for (int off = 1; off < 64; off <<= 1) s += __shfl_xor(s, off);
    __syncthreads();
    if (lane == 0) red[wv] = s;
    __syncthreads();
    s = red[0] + red[1] + red[2] + red[3];
    float lse = mx + __logf(s);
    #pragma unroll
    for (int i = 0; i < 4; ++i) out[b * 1024 + i * 256 + tid] = v[i] - lse;
}

extern "C" void kernel_launch(void* const* d_in, const int* in_sizes, int n_in,
                              void* d_out, int out_size, void* d_ws, size_t ws_size,
                              hipStream_t stream) {
    const float* x    = (const float*)d_in[0];
    const float* Wf   = (const float*)d_in[1];
    const float* bfv  = (const float*)d_in[2];
    const float* Wi   = (const float*)d_in[3];
    const float* biv  = (const float*)d_in[4];
    const float* Wg   = (const float*)d_in[5];
    const float* bgv  = (const float*)d_in[6];
    const float* Wo   = (const float*)d_in[7];
    const float* bov  = (const float*)d_in[8];
    const float* Wout = (const float*)d_in[9];
    const float* bout = (const float*)d_in[10];
    float* out = (float*)d_out;

    // ws layout (~1.1 MB)
    char* p = (char*)d_ws;
    bf16* hbuf    = (bf16*)p;  p += (size_t)2 * 131072 * 2;   // h double-buffer
    float* logits = (float*)p; p += (size_t)131072 * 4;
    unsigned int* bar = (unsigned int*)p; p += 128;
    if (ws_size < (size_t)(p - (char*)d_ws)) return;

    init_kernel<<<128, 256, 0, stream>>>(hbuf, bar);
    lstm_persist<<<NWG, 512, 0, stream>>>(x, Wf, bfv, Wi, biv, Wg, bgv, Wo, bov,
                                          hbuf, bar);
    // t=255 writes hbuf buffer 0
    final_gemm_kernel<<<64, 512, 0, stream>>>(hbuf, Wout, bout, logits);
    logsoftmax_kernel<<<128, 256, 0, stream>>>(logits, out);
}

// Round 4
// 2484.740 us; speedup vs baseline: 6.3337x; 2.3572x over previous
//
#include <hip/hip_runtime.h>

typedef __bf16 bf16;
typedef __bf16 bf16x8 __attribute__((ext_vector_type(8)));
typedef float f32x4 __attribute__((ext_vector_type(4)));
typedef unsigned int u32x4 __attribute__((ext_vector_type(4)));

#define T_STEPS 256
#define NWG 256

__device__ __forceinline__ float sigmoidf_(float v) { return 1.0f / (1.0f + __expf(-v)); }

__global__ void init_kernel(bf16* __restrict__ hb0, unsigned int* __restrict__ bar) {
    int gid = blockIdx.x * blockDim.x + threadIdx.x;  // 32768 threads
    #pragma unroll
    for (int i = 0; i < 4; ++i) hb0[gid + i * 32768] = (bf16)0.0f;
    if (gid == 0) { bar[0] = 0u; bar[32] = 0u; bar[64] = 0u; bar[96] = 0u; }
}

// ---------------------------------------------------------------------------
// Persistent LSTM: 256 WGs x 512 thr (1/CU). WG = (mq = batch rows [32mq,+32),
// tile = hidden cols [16t,+16) x 4 gates). Weights persistent in VGPRs.
// Coherence WITHOUT fences: h stores are system-scope write-through (sc0 sc1),
// h loads are system-scope inline-asm dwordx4 (bypass L1/L2). Barrier is a
// relaxed agent RMW per WG, 4 independent groups (one per batch quarter).
// No buffer_wbl2 / buffer_inv in the loop -> x and weight lines stay cached.
// ---------------------------------------------------------------------------
__global__ __launch_bounds__(512, 2) void lstm_persist(
    const float* __restrict__ x,
    const float* __restrict__ Wf, const float* __restrict__ bfp,
    const float* __restrict__ Wi, const float* __restrict__ bip,
    const float* __restrict__ Wg, const float* __restrict__ bgp,
    const float* __restrict__ Wo, const float* __restrict__ bop,
    bf16* __restrict__ hb, unsigned int* __restrict__ bar)
{
    __shared__ bf16 S[32 * 2048];     // 128 KB: row pitch 2048 els; 16B chunk c at slot c^(row&7)
    __shared__ float zbuf[6336];      // 25 KB: 6 partial bufs [32][33]; overlaid zfull [32][65]

    const int wg    = blockIdx.x;
    const int mq    = wg & 3;
    const int tile  = wg >> 2;
    const int tid   = threadIdx.x;
    const int lane  = tid & 63;
    const int w     = tid >> 6;
    const int kq    = w & 3;          // K quarter (0,1 = x half; 2,3 = h half)
    const int gpair = w >> 2;         // gates {0,1} or {2,3}
    const int l16   = lane & 15;
    const int l4    = lane >> 4;
    unsigned int* mybar = bar + mq * 32;   // per-batch-quarter barrier

    // ---- persistent B fragments: gate g = gpair*2+nt, k = kq*512 + ks*32 + l4*8
    bf16x8 bfrag[2][16];
    {
        const float* Wg0 = gpair ? Wg : Wf;
        const float* Wg1 = gpair ? Wo : Wi;
        #pragma unroll
        for (int nt = 0; nt < 2; ++nt) {
            const float* wrow = (nt ? Wg1 : Wg0) + (size_t)(tile * 16 + l16) * 2048 + kq * 512 + l4 * 8;
            #pragma unroll
            for (int ks = 0; ks < 16; ++ks) {
                float4 a = *(const float4*)(wrow + ks * 32);
                float4 b = *(const float4*)(wrow + ks * 32 + 4);
                bf16x8 f;
                f[0]=(bf16)a.x; f[1]=(bf16)a.y; f[2]=(bf16)a.z; f[3]=(bf16)a.w;
                f[4]=(bf16)b.x; f[5]=(bf16)b.y; f[6]=(bf16)b.z; f[7]=(bf16)b.w;
                bfrag[nt][ks] = f;
            }
        }
    }

    // ---- combine ownership: threads 0..255, each owns (row cb, col pair cp)
    const int cb = tid >> 3;          // 0..31
    const int cp = tid & 7;           // col pair: cols 2cp, 2cp+1
    float bias0[2], bias1[2], bias2[2], bias3[2];
    if (tid < 256) {
        #pragma unroll
        for (int j = 0; j < 2; ++j) {
            int col = tile * 16 + 2 * cp + j;
            bias0[j] = bfp[col];  // gate0 -> i_t (ref naming swap)
            bias1[j] = bip[col];  // gate1 -> f_t
            bias2[j] = bgp[col];  // gate2 -> g_t
            bias3[j] = bop[col];  // gate3 -> o_t
        }
    }
    float creg0 = 0.0f, creg1 = 0.0f;

    unsigned int goal = 0;
    for (int t = 0; t < T_STEPS; ++t) {
        // ---- stage x half (immutable, cached): overlaps barrier wait
        {
            const int row = tid >> 4, cl = tid & 15;
            const float* gsrc = x + (size_t)t * 131072 + (size_t)(mq * 32 + row) * 1024;
            #pragma unroll
            for (int j = 0; j < 8; ++j) {
                int c = cl + j * 16;               // chunk 0..127 (x half)
                float4 v0 = *(const float4*)(gsrc + c * 8);
                float4 v1 = *(const float4*)(gsrc + c * 8 + 4);
                bf16x8 f;
                f[0]=(bf16)v0.x; f[1]=(bf16)v0.y; f[2]=(bf16)v0.z; f[3]=(bf16)v0.w;
                f[4]=(bf16)v1.x; f[5]=(bf16)v1.y; f[6]=(bf16)v1.z; f[7]=(bf16)v1.w;
                *(bf16x8*)(&S[row * 2048 + (c ^ (row & 7)) * 8]) = f;
            }
        }
        // ---- wait: h(t) globally visible (t=0 from init kernel)
        if (t > 0) {
            goal += 64;
            if (tid == 0) {
                while (__hip_atomic_load(mybar, __ATOMIC_RELAXED, __HIP_MEMORY_SCOPE_AGENT) < goal)
                    __builtin_amdgcn_s_sleep(1);
            }
            __syncthreads();
        }
        // ---- stage h half: system-scope loads (bypass L1/L2, read MALL)
        {
            const bf16* hcur = hb + (t & 1) * 131072;
            u32x4 tmp[8];
            #pragma unroll
            for (int r = 0; r < 4; ++r) {
                int row = w * 4 + r;
                #pragma unroll
                for (int q = 2; q < 4; ++q) {
                    int slot = q * 64 + lane;          // LDS chunk slot
                    int c    = slot ^ (row & 7);       // global chunk
                    const void* g = hcur + (size_t)(mq * 32 + row) * 1024 + (c - 128) * 8;
                    asm volatile("global_load_dwordx4 %0, %1, off sc0 sc1"
                                 : "=v"(tmp[r * 2 + (q - 2)]) : "v"(g));
                }
            }
            asm volatile("s_waitcnt vmcnt(0)" ::: "memory");
            #pragma unroll
            for (int r = 0; r < 4; ++r) {
                int row = w * 4 + r;
                #pragma unroll
                for (int q = 2; q < 4; ++q) {
                    int slot = q * 64 + lane;
                    *(u32x4*)(&S[row * 2048 + slot * 8]) = tmp[r * 2 + (q - 2)];
                }
            }
        }
        __syncthreads();

        // ---- GEMM: wave computes 32m x 32n over its 512-wide k slice
        f32x4 acc[2][2];
        acc[0][0] = acc[0][1] = acc[1][0] = acc[1][1] = (f32x4){0.f, 0.f, 0.f, 0.f};
        #pragma unroll
        for (int ks = 0; ks < 16; ++ks) {
            bf16x8 af[2];
            #pragma unroll
            for (int mt = 0; mt < 2; ++mt) {
                int row = mt * 16 + l16;
                int c   = kq * 64 + ks * 4 + l4;
                af[mt] = *(const bf16x8*)(&S[row * 2048 + (c ^ (l16 & 7)) * 8]);
            }
            #pragma unroll
            for (int mt = 0; mt < 2; ++mt)
                #pragma unroll
                for (int nt = 0; nt < 2; ++nt)
                    acc[mt][nt] = __builtin_amdgcn_mfma_f32_16x16x32_bf16(
                        af[mt], bfrag[nt][ks], acc[mt][nt], 0, 0, 0);
        }
        __syncthreads();

        // ---- intra-WG K-reduction (kq 1..3 -> kq 0); C/D: row=l4*4+r, col=l16
        if (kq != 0) {
            float* pb = zbuf + (gpair * 3 + (kq - 1)) * 1056;
            #pragma unroll
            for (int mt = 0; mt < 2; ++mt)
                #pragma unroll
                for (int nt = 0; nt < 2; ++nt)
                    #pragma unroll
                    for (int r = 0; r < 4; ++r)
                        pb[(mt * 16 + l4 * 4 + r) * 33 + nt * 16 + l16] = acc[mt][nt][r];
        }
        __syncthreads();
        if (kq == 0) {
            #pragma unroll
            for (int s = 0; s < 3; ++s) {
                const float* pb = zbuf + (gpair * 3 + s) * 1056;
                #pragma unroll
                for (int mt = 0; mt < 2; ++mt)
                    #pragma unroll
                    for (int nt = 0; nt < 2; ++nt)
                        #pragma unroll
                        for (int r = 0; r < 4; ++r)
                            acc[mt][nt][r] += pb[(mt * 16 + l4 * 4 + r) * 33 + nt * 16 + l16];
            }
        }
        __syncthreads();
        if (kq == 0) {  // full z [32][64] (pitch 65) overlaid on zbuf
            #pragma unroll
            for (int mt = 0; mt < 2; ++mt)
                #pragma unroll
                for (int nt = 0; nt < 2; ++nt)
                    #pragma unroll
                    for (int r = 0; r < 4; ++r)
                        zbuf[(mt * 16 + l4 * 4 + r) * 65 + gpair * 32 + nt * 16 + l16] = acc[mt][nt][r];
        }
        __syncthreads();

        // ---- gate combine: thread owns (cb, cols 2cp/2cp+1); packed h store
        if (tid < 256) {
            float hv[2];
            #pragma unroll
            for (int j = 0; j < 2; ++j) {
                int col = 2 * cp + j;
                float zi = zbuf[cb * 65 + 0  + col] + bias0[j];
                float zf = zbuf[cb * 65 + 16 + col] + bias1[j];
                float zg = zbuf[cb * 65 + 32 + col] + bias2[j];
                float zo = zbuf[cb * 65 + 48 + col] + bias3[j];
                float ig = sigmoidf_(zi), fg = sigmoidf_(zf);
                float gg = tanhf(zg),     og = sigmoidf_(zo);
                float& cr = j ? creg1 : creg0;
                cr = fg * cr + ig * gg;
                hv[j] = og * tanhf(cr);
            }
            unsigned short u0 = __builtin_bit_cast(unsigned short, (bf16)hv[0]);
            unsigned short u1 = __builtin_bit_cast(unsigned short, (bf16)hv[1]);
            unsigned int packed = ((unsigned int)u1 << 16) | u0;
            unsigned int* dst = (unsigned int*)(hb + ((t + 1) & 1) * 131072
                                + (size_t)(mq * 32 + cb) * 1024 + tile * 16 + 2 * cp);
            // system-scope write-through: lands at coherent point, no wbl2 needed
            __hip_atomic_store(dst, packed, __ATOMIC_RELAXED, __HIP_MEMORY_SCOPE_SYSTEM);
        }
        // ---- arrive: per-thread store-ack, then one relaxed RMW per WG
        asm volatile("s_waitcnt vmcnt(0)" ::: "memory");
        __syncthreads();
        if (tid == 0)
            __hip_atomic_fetch_add(mybar, 1u, __ATOMIC_RELAXED, __HIP_MEMORY_SCOPE_AGENT);
    }
}

// ---------------------------------------------------------------------------
// logits = h_T @ Wout^T + bout (Wout converted inline from f32).
// ---------------------------------------------------------------------------
__global__ __launch_bounds__(512) void final_gemm_kernel(
    const bf16* __restrict__ hfin, const float* __restrict__ Wout,
    const float* __restrict__ bout, float* __restrict__ logits) {
    __shared__ alignas(16) bf16 Slds[128 * 72];
    const int tid  = threadIdx.x;
    const int lane = tid & 63;
    const int wave = tid >> 6;
    const int l16  = lane & 15;
    const int l4   = lane >> 4;
    const int n0   = blockIdx.x * 16;
    f32x4 acc = (f32x4){0.f, 0.f, 0.f, 0.f};
    for (int k0 = 0; k0 < 1024; k0 += 64) {
        #pragma unroll
        for (int i = 0; i < 2; ++i) {
            int cidx = tid + i * 512;
            int row = cidx >> 3, c8 = cidx & 7;
            *(uint4*)(&Slds[row * 72 + c8 * 8]) =
                *(const uint4*)(hfin + row * 1024 + k0 + c8 * 8);
        }
        __syncthreads();
        #pragma unroll
        for (int kk = 0; kk < 64; kk += 32) {
            const float* wrow = Wout + (size_t)(n0 + l16) * 1024 + k0 + kk + l4 * 8;
            float4 w0 = *(const float4*)(wrow);
            float4 w1 = *(const float4*)(wrow + 4);
            bf16x8 bfrag;
            bfrag[0]=(bf16)w0.x; bfrag[1]=(bf16)w0.y; bfrag[2]=(bf16)w0.z; bfrag[3]=(bf16)w0.w;
            bfrag[4]=(bf16)w1.x; bfrag[5]=(bf16)w1.y; bfrag[6]=(bf16)w1.z; bfrag[7]=(bf16)w1.w;
            bf16x8 afrag = *(const bf16x8*)(&Slds[(wave * 16 + l16) * 72 + kk + l4 * 8]);
            acc = __builtin_amdgcn_mfma_f32_16x16x32_bf16(afrag, bfrag, acc, 0, 0, 0);
        }
        __syncthreads();
    }
    float bv = bout[n0 + l16];
    #pragma unroll
    for (int r = 0; r < 4; ++r) {
        int m = wave * 16 + l4 * 4 + r;
        logits[m * 1024 + n0 + l16] = acc[r] + bv;
    }
}

// ---------------------------------------------------------------------------
// Row-wise log_softmax over 1024 logits. Grid 128 (one WG per batch row).
// ---------------------------------------------------------------------------
__global__ __launch_bounds__(256) void logsoftmax_kernel(
    const float* __restrict__ logits, float* __restrict__ out) {
    int b = blockIdx.x, tid = threadIdx.x;
    int lane = tid & 63, wv = tid >> 6;
    __shared__ float red[4];
    float v[4];
    float mx = -1e30f;
    #pragma unroll
    for (int i = 0; i < 4; ++i) {
        v[i] = logits[b * 1024 + i * 256 + tid];
        mx = fmaxf(mx, v[i]);
    }
    #pragma unroll
    for (int off = 1; off < 64; off <<= 1) mx = fmaxf(mx, __shfl_xor(mx, off));
    if (lane == 0) red[wv] = mx;
    __syncthreads();
    mx = fmaxf(fmaxf(red[0], red[1]), fmaxf(red[2], red[3]));
    float s = 0.f;
    #pragma unroll
    for (int i = 0; i < 4; ++i) s += __expf(v[i] - mx);
    #pragma unroll
    for (int off = 1; off < 64; off <<= 1) s += __shfl_xor(s, off);
    __syncthreads();
    if (lane == 0) red[wv] = s;
    __syncthreads();
    s = red[0] + red[1] + red[2] + red[3];
    float lse = mx + __logf(s);
    #pragma unroll
    for (int i = 0; i < 4; ++i) out[b * 1024 + i * 256 + tid] = v[i] - lse;
}

extern "C" void kernel_launch(void* const* d_in, const int* in_sizes, int n_in,
                              void* d_out, int out_size, void* d_ws, size_t ws_size,
                              hipStream_t stream) {
    const float* x    = (const float*)d_in[0];
    const float* Wf   = (const float*)d_in[1];
    const float* bfv  = (const float*)d_in[2];
    const float* Wi   = (const float*)d_in[3];
    const float* biv  = (const float*)d_in[4];
    const float* Wg   = (const float*)d_in[5];
    const float* bgv  = (const float*)d_in[6];
    const float* Wo   = (const float*)d_in[7];
    const float* bov  = (const float*)d_in[8];
    const float* Wout = (const float*)d_in[9];
    const float* bout = (const float*)d_in[10];
    float* out = (float*)d_out;

    // ws layout (~1.1 MB)
    char* p = (char*)d_ws;
    bf16* hbuf    = (bf16*)p;  p += (size_t)2 * 131072 * 2;   // h double-buffer
    float* logits = (float*)p; p += (size_t)131072 * 4;
    unsigned int* bar = (unsigned int*)p; p += 512;           // 4 counters, 128B apart
    if (ws_size < (size_t)(p - (char*)d_ws)) return;

    init_kernel<<<128, 256, 0, stream>>>(hbuf, bar);
    lstm_persist<<<NWG, 512, 0, stream>>>(x, Wf, bfv, Wi, biv, Wg, bgv, Wo, bov,
                                          hbuf, bar);
    // t=255 writes hbuf buffer 0
    final_gemm_kernel<<<64, 512, 0, stream>>>(hbuf, Wout, bout, logits);
    logsoftmax_kernel<<<128, 256, 0, stream>>>(logits, out);
}